// Round 4
// baseline (750.202 us; speedup 1.0000x reference)
//
#include <hip/hip_runtime.h>
#include <hip/hip_cooperative_groups.h>
#include <math.h>

namespace cg = cooperative_groups;
using uint = unsigned int;
typedef _Float16 h2 __attribute__((ext_vector_type(2)));

#define N_ATOMS 8192
#define NEDGE   262144
#define KNBR    32
#define NGAUSS  50
#define NLAYER  6
#define NB      32
#define GTAB    2048
#define DMAX    8.6603f
#define FCUT    10.0f
#define MB      1048576

// wpack layout (uints)
#define OW1_OFF  147456          // 18*8192 (cf1 x6 | cf2 x6 | int x6)
#define M1_OFF   151552          // +4096 (out_w1 128x64)
#define M2_OFF   176128          // +6*4096 (mlp_w1)
#define WPACK_N  225280          // +6*8192 (mlp_w2)

// smem layout (uint offsets)
#define S_WBUF 0        // 8192 uints: weight buffer (W1/W2/W3/W1n/M1[4096]/table-W1p[4096])
#define S_TW2  4096     // table phase: W2p (8192)
#define S_AS   8192     // As (<=2048)
#define S_TS   10240    // Ts (<=2048)
#define S_F    12288    // float scratch (512) / table rbf (1024)
#define S_TTS  13312    // table hid (2048)
#define SMEM_N 15616    // 62464 B -> 2 blocks/CU by LDS

__device__ __forceinline__ float ssp(float x) {
    return fmaxf(x, 0.0f) + log1pf(expf(-fabsf(x))) - 0.69314718055994531f;
}
__device__ __forceinline__ uint pack2(float a, float b) {
    union { h2 h; uint u; } x;
    h2 v; v.x = (_Float16)a; v.y = (_Float16)b; x.h = v; return x.u;
}
__device__ __forceinline__ h2 u2h(uint u) {
    union { uint u; h2 h; } x; x.u = u; return x.h;
}
__device__ __forceinline__ float2 h2f2(uint u) {
    h2 h = u2h(u); float2 r; r.x = (float)h.x; r.y = (float)h.y; return r;
}
__device__ __forceinline__ float fdot2f(h2 a, h2 b, float c) {
#if __has_builtin(__builtin_amdgcn_fdot2)
    return __builtin_amdgcn_fdot2(a, b, c, false);
#else
    return fmaf((float)a.y, (float)b.y, fmaf((float)a.x, (float)b.x, c));
#endif
}

struct Args {
    const float *pos; const int *z; const int *ei; const int *dom;
    const float *emb;
    const float *mb1; const float *mb2;
    const float *cf2b; const float *intb;
    const float *ob1; const float *ow2; const float *ob2;
    const float *dome; const float *fw1; const float *fb1;
    const float *fw2; const float *fb2; const float *bw; const float *bb;
    const float *cf1; const float *cf2w; const float *intw; const float *ow1;
    const float *mw1; const float *mw2;
    uint2 *epack; uint *tab; float *h; uint *x16; float *atom_e;
    float *gbias; uint *wpack; float *out; int out_size;
};

__device__ __forceinline__ void stage_u4(uint* dst, const uint* src, int nu4, int tid) {
    const uint4* s4 = (const uint4*)src; uint4* d4 = (uint4*)dst;
    for (int i = tid; i < nu4; i += 256) d4[i] = s4[i];
}

// K=64-pair GEMM step: acc[R][4] over As(stride 64) x W(stride 128)
template<int R>
__device__ __forceinline__ void gemm_k64(const uint* __restrict__ sm, int as_off, int w_off,
                                         int r0, int c0, float (*acc)[4]) {
    #pragma unroll 4
    for (int oct = 0; oct < 16; ++oct) {
        int kp0 = oct * 4;
        uint4 w_[4];
        #pragma unroll
        for (int p = 0; p < 4; ++p) w_[p] = *(const uint4*)&sm[w_off + (kp0+p)*128 + c0];
        #pragma unroll
        for (int i = 0; i < R; ++i) {
            uint4 av = *(const uint4*)&sm[as_off + (r0+i)*64 + kp0];
            uint aa[4] = {av.x, av.y, av.z, av.w};
            #pragma unroll
            for (int p = 0; p < 4; ++p) {
                h2 ap = u2h(aa[p]);
                acc[i][0] = fdot2f(ap, u2h(w_[p].x), acc[i][0]);
                acc[i][1] = fdot2f(ap, u2h(w_[p].y), acc[i][1]);
                acc[i][2] = fdot2f(ap, u2h(w_[p].z), acc[i][2]);
                acc[i][3] = fdot2f(ap, u2h(w_[p].w), acc[i][3]);
            }
        }
    }
}

template<int APB>
__device__ void mono_impl(const Args& a) {
    constexpr int NBLK = N_ATOMS / APB;
    constexpr int R = APB / 8;                    // GEMM rows per thread
    __shared__ __align__(16) uint smem[SMEM_N];
    cg::grid_group grid = cg::this_grid();
    const int tid = threadIdx.x;
    const int bid = blockIdx.x;
    const int gsz  = NBLK * 256;
    const int gidx = bid * 256 + tid;
    const int tx = tid & 31, ty = tid >> 5;
    const int c0 = tx * 4, r0 = ty * R;

    // ================= Phase S: film / embed / epack / wcvt / zero-out ========
    if (bid < NB) {   // FiLM beta-sum for graph bid (gamma multiplies zeros)
        float* fs = (float*)&smem[S_F];  // des@0, a1@64, film@192, partial@320
        if (tid < 64) fs[tid] = a.dome[a.dom[bid]*64 + tid];
        __syncthreads();
        if (tid < 128) {
            float acc = a.fb1[tid];
            for (int i = 0; i < 64; ++i) acc = fmaf(fs[i], a.fw1[i*128 + tid], acc);
            fs[64 + tid] = fmaxf(acc, 0.0f);
        }
        __syncthreads();
        if (tid < 128) {
            float acc = a.fb2[tid];
            for (int i = 0; i < 128; ++i) acc = fmaf(fs[64+i], a.fw2[i*128 + tid], acc);
            fs[192 + tid] = acc;
        }
        __syncthreads();
        if (tid < 128) {
            float acc = a.bb[tid];
            for (int i = 0; i < 128; ++i) acc = fmaf(fs[192+i], a.bw[i*128 + tid], acc);
            #pragma unroll
            for (int off = 32; off > 0; off >>= 1) acc += __shfl_down(acc, off, 64);
            if ((tid & 63) == 0) fs[320 + (tid >> 6)] = acc;
        }
        __syncthreads();
        if (tid == 0) a.gbias[bid] = fs[320] + fs[321];
    }
    for (int i = gidx; i < N_ATOMS*128; i += gsz) {      // h = embedding[z]
        int at = i >> 7, f = i & 127;
        a.h[i] = a.emb[a.z[at]*128 + f];
    }
    const float invdelta = (float)(GTAB - 1) / DMAX;     // epack = (src, t|i0)
    for (int e = gidx; e < NEDGE; e += gsz) {
        int s = a.ei[e], d = a.ei[NEDGE + e];
        float dx = a.pos[3*s]-a.pos[3*d], dy = a.pos[3*s+1]-a.pos[3*d+1], dz = a.pos[3*s+2]-a.pos[3*d+2];
        float dist = sqrtf(dx*dx + dy*dy + dz*dz);
        float u = dist * invdelta;
        int i0 = (int)u; i0 = (i0 < GTAB-2) ? i0 : (GTAB-2);
        float t = u - (float)i0;
        uint tb = pack2(t, 0.0f) & 0xffffu;
        uint2 ep; ep.x = (uint)s; ep.y = (tb << 16) | (uint)i0;
        a.epack[e] = ep;
    }
    for (int idx = gidx; idx < WPACK_N; idx += gsz) {    // weight f16 pack
        float va, vb;
        if (idx < OW1_OFF) {
            int m = idx >> 13, e = idx & 8191;
            int kp = e >> 7, cc = e & 127;
            const float* src = (m < 6) ? (a.cf1 + m*16384)
                            : (m < 12) ? (a.cf2w + (m-6)*16384)
                                       : (a.intw + (m-12)*16384);
            va = src[(2*kp)*128 + cc];
            vb = src[(2*kp+1)*128 + cc];
        } else if (idx < M1_OFF) {
            int e = idx - OW1_OFF;
            int kp = e >> 6, cc = e & 63;
            va = a.ow1[(2*kp)*64 + cc];
            vb = a.ow1[(2*kp+1)*64 + cc];
        } else if (idx < M2_OFF) {
            int e = idx - M1_OFF;
            int l = e >> 12, r = e & 4095;
            int kp = r >> 7, cc = r & 127;
            int g0 = 2*kp;
            va = (g0   < NGAUSS) ? a.mw1[l*NGAUSS*128 + g0*128 + cc]     : 0.0f;
            vb = (g0+1 < NGAUSS) ? a.mw1[l*NGAUSS*128 + (g0+1)*128 + cc] : 0.0f;
        } else {
            int e = idx - M2_OFF;
            int l = e >> 13, r = e & 8191;
            int kp = r >> 7, cc = r & 127;
            va = a.mw2[l*16384 + (2*kp)*128 + cc];
            vb = a.mw2[l*16384 + (2*kp+1)*128 + cc];
        }
        a.wpack[idx] = pack2(va, vb);
    }
    for (int i = NB + gidx; i < a.out_size; i += gsz) a.out[i] = 0.0f;  // forces/stress/features

    grid.sync();

    // ================= Phase T: x1 = h @ W1_0, then filter tables ============
    const int rowbase = bid * APB;
    stage_u4(&smem[S_WBUF], a.wpack, 2048, tid);               // W1_0
    {   // As <- h rows (f16 pairs)
        const float4* h4 = (const float4*)(a.h + rowbase*128);
        #pragma unroll
        for (int i = 0; i < R; ++i) {
            int ii = tid + i*256;
            float4 v = h4[ii];
            int row = ii >> 5, fq = ii & 31;
            uint2 rr; rr.x = pack2(v.x, v.y); rr.y = pack2(v.z, v.w);
            *(uint2*)&smem[S_AS + row*64 + fq*2] = rr;
        }
    }
    __syncthreads();
    {
        float acc[R][4];
        #pragma unroll
        for (int i = 0; i < R; ++i) { acc[i][0]=0.f; acc[i][1]=0.f; acc[i][2]=0.f; acc[i][3]=0.f; }
        gemm_k64<R>(smem, S_AS, S_WBUF, r0, c0, acc);
        #pragma unroll
        for (int i = 0; i < R; ++i) {
            uint2 o; o.x = pack2(acc[i][0], acc[i][1]); o.y = pack2(acc[i][2], acc[i][3]);
            *(uint2*)&a.x16[(rowbase + r0 + i)*64 + (c0 >> 1)] = o;
        }
    }
    // tables: 384 chunks of 32 entries
    const float delta = DMAX / (float)(GTAB - 1);
    const float gstep = FCUT / (float)(NGAUSS - 1);
    const float coeff = -0.5f / (gstep * gstep);
    for (int c = bid; c < 384; c += NBLK) {
        __syncthreads();                                   // protect smem reuse
        int l = c >> 6, base = (c & 63) * 32;
        stage_u4(&smem[S_WBUF], a.wpack + M1_OFF + l*4096, 1024, tid);   // W1p (50x128 padded)
        stage_u4(&smem[S_TW2],  a.wpack + M2_OFF + l*8192, 2048, tid);   // W2p (128x128)
        for (int i = tid; i < 1024; i += 256) {            // rbf pairs (32 rows x 32 kp)
            int r = i >> 5, kp = i & 31;
            float dv = (float)(base + r) * delta;
            int g0 = 2*kp;
            float v0 = 0.f, v1 = 0.f;
            if (g0 < NGAUSS)   { float t = dv - (float)g0*gstep;     v0 = expf(coeff*t*t); }
            if (g0+1 < NGAUSS) { float t = dv - (float)(g0+1)*gstep; v1 = expf(coeff*t*t); }
            smem[S_F + i] = pack2(v0, v1);
        }
        __syncthreads();
        int tr0 = ty * 4;
        float acc[4][4];
        #pragma unroll
        for (int i = 0; i < 4; ++i) { acc[i][0]=0.f; acc[i][1]=0.f; acc[i][2]=0.f; acc[i][3]=0.f; }
        #pragma unroll
        for (int oct = 0; oct < 8; ++oct) {                // stage 1: K=50 (32 pairs)
            int kp0 = oct * 4;
            uint4 w_[4];
            #pragma unroll
            for (int p = 0; p < 4; ++p) w_[p] = *(const uint4*)&smem[S_WBUF + (kp0+p)*128 + c0];
            #pragma unroll
            for (int i = 0; i < 4; ++i) {
                uint4 av = *(const uint4*)&smem[S_F + (tr0+i)*32 + kp0];
                uint aa[4] = {av.x, av.y, av.z, av.w};
                #pragma unroll
                for (int p = 0; p < 4; ++p) {
                    h2 ap = u2h(aa[p]);
                    acc[i][0] = fdot2f(ap, u2h(w_[p].x), acc[i][0]);
                    acc[i][1] = fdot2f(ap, u2h(w_[p].y), acc[i][1]);
                    acc[i][2] = fdot2f(ap, u2h(w_[p].z), acc[i][2]);
                    acc[i][3] = fdot2f(ap, u2h(w_[p].w), acc[i][3]);
                }
            }
        }
        float4 b1v = *(const float4*)&a.mb1[l*128 + c0];
        #pragma unroll
        for (int i = 0; i < 4; ++i) {
            float t0 = ssp(acc[i][0] + b1v.x);
            float t1 = ssp(acc[i][1] + b1v.y);
            float t2 = ssp(acc[i][2] + b1v.z);
            float t3 = ssp(acc[i][3] + b1v.w);
            uint2 o; o.x = pack2(t0, t1); o.y = pack2(t2, t3);
            *(uint2*)&smem[S_TTS + (tr0+i)*64 + (c0 >> 1)] = o;
        }
        __syncthreads();
        float acc2[4][4];
        #pragma unroll
        for (int i = 0; i < 4; ++i) { acc2[i][0]=0.f; acc2[i][1]=0.f; acc2[i][2]=0.f; acc2[i][3]=0.f; }
        gemm_k64<4>(smem, S_TTS, S_TW2, tr0, c0, acc2);    // stage 2: K=128
        float4 b2v = *(const float4*)&a.mb2[l*128 + c0];
        #pragma unroll
        for (int i = 0; i < 4; ++i) {
            int row = base + tr0 + i;
            float dv = (float)row * delta;
            float Cd = 0.5f * (cosf(dv * 0.3141592653589793f) + 1.0f);
            uint2 o;
            o.x = pack2((acc2[i][0] + b2v.x)*Cd, (acc2[i][1] + b2v.y)*Cd);
            o.y = pack2((acc2[i][2] + b2v.z)*Cd, (acc2[i][3] + b2v.w)*Cd);
            *(uint2*)&a.tab[(l*GTAB + row)*64 + (c0 >> 1)] = o;
        }
    }
    grid.sync();

    // ================= Layers ===============================================
    for (int l = 0; l < NLAYER; ++l) {
        stage_u4(&smem[S_WBUF], a.wpack + (6+l)*8192, 2048, tid);   // W2
        {   // edge gather -> As
            const uint* tabl = a.tab + l*GTAB*64;
            int tq = tid >> 6, f2 = tid & 63;
            #pragma unroll
            for (int p = 0; p < APB/4; ++p) {
                int al = p*4 + tq;
                int ebase = (rowbase + al) * KNBR;
                float ax = 0.f, ay = 0.f;
                #pragma unroll 4
                for (int k = 0; k < KNBR; ++k) {
                    uint2 ep = a.epack[ebase + k];
                    int s  = (int)ep.x;
                    int i0 = (int)(ep.y & 0xffffu);
                    float t = h2f2(ep.y).y;
                    float2 f0 = h2f2(tabl[i0*64 + f2]);
                    float2 f1 = h2f2(tabl[(i0+1)*64 + f2]);
                    float2 xs = h2f2(a.x16[s*64 + f2]);
                    float wx = fmaf(t, f1.x - f0.x, f0.x);
                    float wy = fmaf(t, f1.y - f0.y, f0.y);
                    ax = fmaf(xs.x, wx, ax);
                    ay = fmaf(xs.y, wy, ay);
                }
                smem[S_AS + al*64 + f2] = pack2(ax, ay);
            }
        }
        __syncthreads();
        {   // Ts = ssp(As @ W2 + b2)
            float acc[R][4];
            #pragma unroll
            for (int i = 0; i < R; ++i) { acc[i][0]=0.f; acc[i][1]=0.f; acc[i][2]=0.f; acc[i][3]=0.f; }
            gemm_k64<R>(smem, S_AS, S_WBUF, r0, c0, acc);
            float4 bv = *(const float4*)&a.cf2b[l*128 + c0];
            #pragma unroll
            for (int i = 0; i < R; ++i) {
                float t0 = ssp(acc[i][0] + bv.x);
                float t1 = ssp(acc[i][1] + bv.y);
                float t2 = ssp(acc[i][2] + bv.z);
                float t3 = ssp(acc[i][3] + bv.w);
                uint2 o; o.x = pack2(t0, t1); o.y = pack2(t2, t3);
                *(uint2*)&smem[S_TS + (r0+i)*64 + (c0 >> 1)] = o;
            }
        }
        __syncthreads();
        stage_u4(&smem[S_WBUF], a.wpack + (12+l)*8192, 2048, tid);  // W3
        __syncthreads();
        {   // h += Ts @ W3 + b3 ; As <- h_new pairs
            float acc2[R][4];
            #pragma unroll
            for (int i = 0; i < R; ++i) { acc2[i][0]=0.f; acc2[i][1]=0.f; acc2[i][2]=0.f; acc2[i][3]=0.f; }
            gemm_k64<R>(smem, S_TS, S_WBUF, r0, c0, acc2);
            float4 b3v = *(const float4*)&a.intb[l*128 + c0];
            #pragma unroll
            for (int i = 0; i < R; ++i) {
                float* hp = &a.h[(rowbase + r0 + i)*128 + c0];
                float4 hv = *(const float4*)hp;
                hv.x += acc2[i][0] + b3v.x;
                hv.y += acc2[i][1] + b3v.y;
                hv.z += acc2[i][2] + b3v.z;
                hv.w += acc2[i][3] + b3v.w;
                *(float4*)hp = hv;
                uint2 o; o.x = pack2(hv.x, hv.y); o.y = pack2(hv.z, hv.w);
                *(uint2*)&smem[S_AS + (r0+i)*64 + (c0 >> 1)] = o;
            }
        }
        __syncthreads();
        if (l < NLAYER-1) {
            stage_u4(&smem[S_WBUF], a.wpack + (l+1)*8192, 2048, tid);   // W1_{l+1}
            __syncthreads();
            float acc[R][4];
            #pragma unroll
            for (int i = 0; i < R; ++i) { acc[i][0]=0.f; acc[i][1]=0.f; acc[i][2]=0.f; acc[i][3]=0.f; }
            gemm_k64<R>(smem, S_AS, S_WBUF, r0, c0, acc);
            #pragma unroll
            for (int i = 0; i < R; ++i) {
                uint2 o; o.x = pack2(acc[i][0], acc[i][1]); o.y = pack2(acc[i][2], acc[i][3]);
                *(uint2*)&a.x16[(rowbase + r0 + i)*64 + (c0 >> 1)] = o;
            }
        } else {
            stage_u4(&smem[S_WBUF], a.wpack + OW1_OFF, 1024, tid);      // out_w1 pack
            __syncthreads();
            int w = tid >> 6, j = tid & 63;
            float accr[APB/4];
            #pragma unroll
            for (int i = 0; i < APB/4; ++i) accr[i] = 0.f;
            for (int kp = 0; kp < 64; ++kp) {
                h2 wv = u2h(smem[S_WBUF + kp*64 + j]);
                #pragma unroll
                for (int i = 0; i < APB/4; ++i)
                    accr[i] = fdot2f(u2h(smem[S_AS + (w*(APB/4)+i)*64 + kp]), wv, accr[i]);
            }
            float b1j = a.ob1[j], w2j = a.ow2[j], b2s = a.ob2[0];
            #pragma unroll
            for (int i = 0; i < APB/4; ++i) {
                float pe = ssp(accr[i] + b1j) * w2j;
                #pragma unroll
                for (int m = 32; m > 0; m >>= 1) pe += __shfl_xor(pe, m, 64);
                if (j == 0) a.atom_e[rowbase + w*(APB/4) + i] = pe + b2s;
            }
        }
        grid.sync();
    }

    // ================= Finish ===============================================
    if (bid < NB) {
        float* red = (float*)&smem[S_F];
        red[tid] = a.atom_e[bid*256 + tid];
        __syncthreads();
        for (int s = 128; s > 0; s >>= 1) {
            if (tid < s) red[tid] += red[tid + s];
            __syncthreads();
        }
        if (tid == 0) {
            float sb = 0.f;
            for (int b = 0; b < NB; ++b) sb += a.gbias[b];
            a.out[bid] = 32.0f * red[0] + sb;
        }
    }
}

__global__ void __launch_bounds__(256, 2) k_mono16(Args a) { mono_impl<16>(a); }
__global__ void __launch_bounds__(256, 2) k_mono32(Args a) { mono_impl<32>(a); }

// ---------------------------------------------------------------------------
extern "C" void kernel_launch(void* const* d_in, const int* in_sizes, int n_in,
                              void* d_out, int out_size, void* d_ws, size_t ws_size,
                              hipStream_t stream) {
    Args a;
    a.pos  = (const float*)d_in[0];
    a.z    = (const int*)d_in[1];
    a.ei   = (const int*)d_in[3];
    a.dom  = (const int*)d_in[4];
    a.emb  = (const float*)d_in[5];
    a.mb1  = (const float*)d_in[7];
    a.mb2  = (const float*)d_in[9];
    a.cf2b = (const float*)d_in[12];
    a.intb = (const float*)d_in[14];
    a.ob1  = (const float*)d_in[16];
    a.ow2  = (const float*)d_in[17];
    a.ob2  = (const float*)d_in[18];
    a.dome = (const float*)d_in[19];
    a.fw1  = (const float*)d_in[20];
    a.fb1  = (const float*)d_in[21];
    a.fw2  = (const float*)d_in[22];
    a.fb2  = (const float*)d_in[23];
    a.bw   = (const float*)d_in[26];
    a.bb   = (const float*)d_in[27];
    a.cf1  = (const float*)d_in[10];
    a.cf2w = (const float*)d_in[11];
    a.intw = (const float*)d_in[13];
    a.ow1  = (const float*)d_in[15];
    a.mw1  = (const float*)d_in[6];
    a.mw2  = (const float*)d_in[8];

    char* ws = (char*)d_ws;
    a.epack  = (uint2*)(ws + 0);               // 2 MB
    a.tab    = (uint*)(ws + 2*MB);             // 3 MB
    a.h      = (float*)(ws + 5*MB);            // 4 MB
    a.x16    = (uint*)(ws + 9*MB);             // 2 MB
    a.atom_e = (float*)(ws + 11*MB);           // 32 KB
    a.gbias  = (float*)(ws + 11*MB + 32768);   // 128 B
    a.wpack  = (uint*)(ws + 11*MB + 65536);    // 901 KB
    a.out = (float*)d_out;
    a.out_size = out_size;

    int occ16 = 0;
    hipOccupancyMaxActiveBlocksPerMultiprocessor(&occ16, (const void*)k_mono16, 256, 0);
    void* kargs[] = { (void*)&a };
    if (occ16 >= 2) {
        hipLaunchCooperativeKernel((const void*)k_mono16, dim3(512), dim3(256), kargs, 0, stream);
    } else {
        hipLaunchCooperativeKernel((const void*)k_mono32, dim3(256), dim3(256), kargs, 0, stream);
    }
}

// Round 5
// 343.359 us; speedup vs baseline: 2.1849x; 2.1849x over previous
//
#include <hip/hip_runtime.h>
#include <math.h>

using uint = unsigned int;
typedef _Float16 h2   __attribute__((ext_vector_type(2)));
typedef _Float16 f16x8 __attribute__((ext_vector_type(8)));
typedef float    f32x4 __attribute__((ext_vector_type(4)));

#define N_ATOMS 8192
#define NEDGE   262144
#define KNBR    32
#define NGAUSS  50
#define NLAYER  6
#define NB      32
#define GTAB    2048
#define DMAX    8.6603f
#define FCUT    10.0f
#define MB      1048576

// LDS geometry (uints). Pad stride 76: 16B-aligned frags, 2-way banks (free).
#define LSTRIDE 76
#define S_WT    0               // 128*76 = 9728
#define S_AS    9728            // 16*76 = 1216
#define S_TS    10944           // 1216
#define LAY_SMEM 12160          // 48.6 KB

// setup table-phase regions
#define T_W1   0
#define T_W2   4096
#define T_RBF  12288
#define T_HID  13312
#define SET_SMEM 15616          // 62.5 KB

// wpack (uints): 18 mats 128x128 in (c,kp) order, then ow1^T 64x64
#define OW1P_OFF 147456
#define WPACK_N  151552

__device__ __forceinline__ float ssp(float x) {
    return fmaxf(x, 0.0f) + log1pf(expf(-fabsf(x))) - 0.69314718055994531f;
}
__device__ __forceinline__ uint pack2(float a, float b) {
    union { h2 h; uint u; } x;
    h2 v; v.x = (_Float16)a; v.y = (_Float16)b; x.h = v; return x.u;
}
__device__ __forceinline__ float2 h2f2(uint u) {
    union { uint u; h2 h; } x; x.u = u;
    float2 r; r.x = (float)x.h.x; r.y = (float)x.h.y; return r;
}
__device__ __forceinline__ float fdot2f(h2 a, h2 b, float c) {
#if __has_builtin(__builtin_amdgcn_fdot2)
    return __builtin_amdgcn_fdot2(a, b, c, false);
#else
    return fmaf((float)a.y, (float)b.y, fmaf((float)a.x, (float)b.x, c));
#endif
}
__device__ __forceinline__ h2 u2h(uint u) {
    union { uint u; h2 h; } x; x.u = u; return x.h;
}

// copy pre-packed W^T (c,kp) 64-stride -> LDS stride-76
__device__ __forceinline__ void stage_cp(uint* sm, const uint* __restrict__ src,
                                         int n16, int tid) {
    for (int i = tid; i < n16; i += 256) {
        uint4 v = ((const uint4*)src)[i];
        *(uint4*)&sm[(i >> 4) * LSTRIDE + (i & 15) * 4] = v;
    }
}

// MFMA: D[16 rows][NCT*16 cols] = As(16x128) @ WT^T, cols base nb
template<int NCT>
__device__ __forceinline__ void run_gemm(const uint* sm, int as_off, int lane,
                                         int nb, f32x4* acc) {
    int m = lane & 15, q = lane >> 4;
    #pragma unroll
    for (int ks = 0; ks < 4; ++ks) {
        f16x8 a = *(const f16x8*)&sm[as_off + m * LSTRIDE + q * 4 + ks * 16];
        #pragma unroll
        for (int ct = 0; ct < NCT; ++ct) {
            f16x8 b = *(const f16x8*)&sm[S_WT + (nb + ct * 16 + m) * LSTRIDE + q * 4 + ks * 16];
            acc[ct] = __builtin_amdgcn_mfma_f32_16x16x32_f16(a, b, acc[ct], 0, 0, 0);
        }
    }
}

struct SArgs {
    const float *pos; const int *z; const int *ei; const int *dom;
    const float *emb;
    const float *cf1; const float *cf2w; const float *intw; const float *ow1;
    const float *mw1; const float *mb1; const float *mw2; const float *mb2;
    const float *dome; const float *fw1; const float *fb1;
    const float *fw2; const float *fb2; const float *bw; const float *bb;
    uint2 *epack; uint *tab; float *h; uint *xA;
    float *e_graph; float *gbias; uint *wpack; float *out; int out_size;
};

// ---------------------------------------------------------------------------
// setup: zero-out + epack + wcvt + embed + x0 GEMM + film + filter tables
__global__ void __launch_bounds__(256) k_setup(SArgs a) {
    __shared__ __align__(16) uint sm[SET_SMEM];
    const int tid = threadIdx.x, bid = blockIdx.x;
    const int gidx = bid * 256 + tid, gsz = 512 * 256;
    const int lane = tid & 63, w = tid >> 6;
    const int m = lane & 15, q = lane >> 4;
    const int rowbase = bid * 16;

    for (int i = 32 + gidx; i < a.out_size; i += gsz) a.out[i] = 0.0f;
    if (gidx < NB) a.e_graph[gidx] = 0.0f;

    // f16 (c,kp)-ordered weight pack for layer kernels
    for (int idx = gidx; idx < WPACK_N; idx += gsz) {
        if (idx < OW1P_OFF) {
            int mat = idx >> 13, e = idx & 8191;
            int kp = e >> 7, c = e & 127;
            const float* src = (mat < 6) ? (a.cf1 + mat * 16384)
                            : (mat < 12) ? (a.cf2w + (mat - 6) * 16384)
                                         : (a.intw + (mat - 12) * 16384);
            a.wpack[mat * 8192 + c * 64 + kp] =
                pack2(src[2 * kp * 128 + c], src[(2 * kp + 1) * 128 + c]);
        } else {
            int e = idx - OW1P_OFF;
            int kp = e >> 6, c = e & 63;
            a.wpack[OW1P_OFF + c * 64 + kp] =
                pack2(a.ow1[2 * kp * 64 + c], a.ow1[(2 * kp + 1) * 64 + c]);
        }
    }

    // epack: local 512 edges
    const float invdelta = (float)(GTAB - 1) / DMAX;
    #pragma unroll
    for (int t = 0; t < 2; ++t) {
        int e = rowbase * KNBR + t * 256 + tid;
        int s = a.ei[e], d = a.ei[NEDGE + e];
        float dx = a.pos[3*s] - a.pos[3*d];
        float dy = a.pos[3*s+1] - a.pos[3*d+1];
        float dz = a.pos[3*s+2] - a.pos[3*d+2];
        float dist = sqrtf(dx*dx + dy*dy + dz*dz);
        float u = dist * invdelta;
        int i0 = (int)u; i0 = (i0 < GTAB - 2) ? i0 : (GTAB - 2);
        float t2 = u - (float)i0;
        uint tb = pack2(t2, 0.0f) & 0xffffu;
        uint2 ep; ep.x = (uint)s; ep.y = (tb << 16) | (uint)i0;
        a.epack[e] = ep;
    }

    // embed -> h (f32) + As (f16)
    for (int i = tid; i < 1024; i += 256) {
        int r = i >> 6, f2 = i & 63;
        int zz = a.z[rowbase + r];
        float2 v = *(const float2*)&a.emb[zz * 128 + f2 * 2];
        *(float2*)&a.h[(rowbase + r) * 128 + f2 * 2] = v;
        sm[S_AS + r * LSTRIDE + f2] = pack2(v.x, v.y);
    }
    // WT <- cf1_0 (fp32 direct, wpack not yet visible)
    for (int i = tid; i < 2048; i += 256) {
        int m4 = i >> 7, c = i & 127;
        float v[8];
        #pragma unroll
        for (int j = 0; j < 8; ++j) v[j] = a.cf1[(8 * m4 + j) * 128 + c];
        uint4 pk; pk.x = pack2(v[0], v[1]); pk.y = pack2(v[2], v[3]);
        pk.z = pack2(v[4], v[5]); pk.w = pack2(v[6], v[7]);
        *(uint4*)&sm[c * LSTRIDE + m4 * 4] = pk;
    }
    __syncthreads();
    {   // x0 = h @ W1_0 -> xA
        f32x4 acc[2] = {{0,0,0,0},{0,0,0,0}};
        run_gemm<2>(sm, S_AS, lane, w * 32, acc);
        #pragma unroll
        for (int ct = 0; ct < 2; ++ct) {
            int n = w * 32 + ct * 16 + m;
            #pragma unroll
            for (int i = 0; i < 4; ++i) {
                float v = acc[ct][i];
                float u = __shfl_xor(v, 1, 64);
                if (!(lane & 1))
                    a.xA[(rowbase + q * 4 + i) * 64 + (n >> 1)] = pack2(v, u);
            }
        }
    }
    __syncthreads();
    // FiLM beta sum (gamma path multiplies zeros)
    if (bid < NB) {
        float* fs = (float*)sm;   // des@0, a1@64, film@192, part@320
        if (tid < 64) fs[tid] = a.dome[a.dom[bid] * 64 + tid];
        __syncthreads();
        if (tid < 128) {
            float acc = a.fb1[tid];
            for (int i = 0; i < 64; ++i) acc = fmaf(fs[i], a.fw1[i*128 + tid], acc);
            fs[64 + tid] = fmaxf(acc, 0.0f);
        }
        __syncthreads();
        if (tid < 128) {
            float acc = a.fb2[tid];
            for (int i = 0; i < 128; ++i) acc = fmaf(fs[64+i], a.fw2[i*128 + tid], acc);
            fs[192 + tid] = acc;
        }
        __syncthreads();
        if (tid < 128) {
            float acc = a.bb[tid];
            for (int i = 0; i < 128; ++i) acc = fmaf(fs[192+i], a.bw[i*128 + tid], acc);
            #pragma unroll
            for (int off = 32; off > 0; off >>= 1) acc += __shfl_down(acc, off, 64);
            if ((tid & 63) == 0) fs[320 + (tid >> 6)] = acc;
        }
        __syncthreads();
        if (tid == 0) a.gbias[bid] = fs[320] + fs[321];
    }
    __syncthreads();
    // filter tables: 384 chunks of 32 entries (dot2 GEMM, inline f16 convert)
    if (bid < 384) {
        int l = bid >> 6, base = (bid & 63) * 32;
        for (int i = tid; i < 4096; i += 256) {
            int kp = i >> 7, c = i & 127;
            int g0 = 2 * kp;
            float va = (g0 < NGAUSS)     ? a.mw1[l*NGAUSS*128 + g0*128 + c]       : 0.f;
            float vb = (g0 + 1 < NGAUSS) ? a.mw1[l*NGAUSS*128 + (g0+1)*128 + c]   : 0.f;
            sm[T_W1 + i] = pack2(va, vb);
        }
        for (int i = tid; i < 8192; i += 256) {
            int kp = i >> 7, c = i & 127;
            sm[T_W2 + i] = pack2(a.mw2[l*16384 + 2*kp*128 + c],
                                 a.mw2[l*16384 + (2*kp+1)*128 + c]);
        }
        const float delta = DMAX / (float)(GTAB - 1);
        const float gstep = FCUT / (float)(NGAUSS - 1);
        const float coeff = -0.5f / (gstep * gstep);
        for (int i = tid; i < 1024; i += 256) {
            int r = i >> 5, kp = i & 31;
            float dv = (float)(base + r) * delta;
            int g0 = 2 * kp;
            float v0 = 0.f, v1 = 0.f;
            if (g0 < NGAUSS)     { float t = dv - (float)g0*gstep;     v0 = expf(coeff*t*t); }
            if (g0 + 1 < NGAUSS) { float t = dv - (float)(g0+1)*gstep; v1 = expf(coeff*t*t); }
            sm[T_RBF + i] = pack2(v0, v1);
        }
        __syncthreads();
        int tx = tid & 31, ty = tid >> 5, c0 = tx * 4, tr0 = ty * 4;
        float acc[4][4];
        #pragma unroll
        for (int i = 0; i < 4; ++i) { acc[i][0]=0.f; acc[i][1]=0.f; acc[i][2]=0.f; acc[i][3]=0.f; }
        #pragma unroll
        for (int oct = 0; oct < 8; ++oct) {
            int kp0 = oct * 4;
            uint4 w_[4];
            #pragma unroll
            for (int p = 0; p < 4; ++p) w_[p] = *(const uint4*)&sm[T_W1 + (kp0+p)*128 + c0];
            #pragma unroll
            for (int i = 0; i < 4; ++i) {
                uint4 av = *(const uint4*)&sm[T_RBF + (tr0+i)*32 + kp0];
                uint aa[4] = {av.x, av.y, av.z, av.w};
                #pragma unroll
                for (int p = 0; p < 4; ++p) {
                    h2 ap = u2h(aa[p]);
                    acc[i][0] = fdot2f(ap, u2h(w_[p].x), acc[i][0]);
                    acc[i][1] = fdot2f(ap, u2h(w_[p].y), acc[i][1]);
                    acc[i][2] = fdot2f(ap, u2h(w_[p].z), acc[i][2]);
                    acc[i][3] = fdot2f(ap, u2h(w_[p].w), acc[i][3]);
                }
            }
        }
        float4 b1v = *(const float4*)&a.mb1[l*128 + c0];
        #pragma unroll
        for (int i = 0; i < 4; ++i) {
            uint2 o;
            o.x = pack2(ssp(acc[i][0] + b1v.x), ssp(acc[i][1] + b1v.y));
            o.y = pack2(ssp(acc[i][2] + b1v.z), ssp(acc[i][3] + b1v.w));
            *(uint2*)&sm[T_HID + (tr0+i)*64 + (c0 >> 1)] = o;
        }
        __syncthreads();
        float acc2[4][4];
        #pragma unroll
        for (int i = 0; i < 4; ++i) { acc2[i][0]=0.f; acc2[i][1]=0.f; acc2[i][2]=0.f; acc2[i][3]=0.f; }
        #pragma unroll 4
        for (int oct = 0; oct < 16; ++oct) {
            int kp0 = oct * 4;
            uint4 w_[4];
            #pragma unroll
            for (int p = 0; p < 4; ++p) w_[p] = *(const uint4*)&sm[T_W2 + (kp0+p)*128 + c0];
            #pragma unroll
            for (int i = 0; i < 4; ++i) {
                uint4 av = *(const uint4*)&sm[T_HID + (tr0+i)*64 + kp0];
                uint aa[4] = {av.x, av.y, av.z, av.w};
                #pragma unroll
                for (int p = 0; p < 4; ++p) {
                    h2 ap = u2h(aa[p]);
                    acc2[i][0] = fdot2f(ap, u2h(w_[p].x), acc2[i][0]);
                    acc2[i][1] = fdot2f(ap, u2h(w_[p].y), acc2[i][1]);
                    acc2[i][2] = fdot2f(ap, u2h(w_[p].z), acc2[i][2]);
                    acc2[i][3] = fdot2f(ap, u2h(w_[p].w), acc2[i][3]);
                }
            }
        }
        float4 b2v = *(const float4*)&a.mb2[l*128 + c0];
        #pragma unroll
        for (int i = 0; i < 4; ++i) {
            int row = base + tr0 + i;
            float dv = (float)row * delta;
            float Cd = 0.5f * (cosf(dv * 0.3141592653589793f) + 1.0f);
            uint2 o;
            o.x = pack2((acc2[i][0] + b2v.x)*Cd, (acc2[i][1] + b2v.y)*Cd);
            o.y = pack2((acc2[i][2] + b2v.z)*Cd, (acc2[i][3] + b2v.w)*Cd);
            *(uint2*)&a.tab[(l*GTAB + row)*64 + (c0 >> 1)] = o;
        }
    }
}

// ---------------------------------------------------------------------------
// fused layer: gather -> ssp(.@W2+b2) -> h += .@W3+b3 -> x_next = h@W1n  (MFMA)
template<bool LAST>
__global__ void __launch_bounds__(256) k_layer(
    float* __restrict__ h, const uint* __restrict__ xin, uint* __restrict__ xout,
    const uint* __restrict__ tabl, const uint2* __restrict__ epack,
    const uint* __restrict__ w2p, const uint* __restrict__ w3p,
    const uint* __restrict__ w1np,
    const float* __restrict__ b2, const float* __restrict__ b3,
    const float* __restrict__ ob1, const float* __restrict__ ow2,
    const float* __restrict__ ob2, float* __restrict__ e_graph) {
    __shared__ __align__(16) uint sm[LAY_SMEM];
    const int tid = threadIdx.x, bid = blockIdx.x;
    const int lane = tid & 63, w = tid >> 6;
    const int m = lane & 15, q = lane >> 4;
    const int rowbase = bid * 16;

    stage_cp(sm, w2p, 2048, tid);
    {   // gather 16 atoms x 32 edges
        int f2 = lane;
        #pragma unroll
        for (int p = 0; p < 4; ++p) {
            int al = p * 4 + w;
            int ebase = (rowbase + al) * KNBR;
            float ax = 0.f, ay = 0.f;
            #pragma unroll 4
            for (int k = 0; k < KNBR; ++k) {
                uint2 ep = epack[ebase + k];
                int s  = (int)ep.x;
                int i0 = (int)(ep.y & 0xffffu);
                float t = h2f2(ep.y).y;
                float2 f0 = h2f2(tabl[i0 * 64 + f2]);
                float2 f1 = h2f2(tabl[(i0 + 1) * 64 + f2]);
                float2 xs = h2f2(xin[s * 64 + f2]);
                ax = fmaf(xs.x, fmaf(t, f1.x - f0.x, f0.x), ax);
                ay = fmaf(xs.y, fmaf(t, f1.y - f0.y, f0.y), ay);
            }
            sm[S_AS + al * LSTRIDE + f2] = pack2(ax, ay);
        }
    }
    __syncthreads();
    {   // Ts = ssp(As @ W2 + b2)
        f32x4 acc[2] = {{0,0,0,0},{0,0,0,0}};
        run_gemm<2>(sm, S_AS, lane, w * 32, acc);
        #pragma unroll
        for (int ct = 0; ct < 2; ++ct) {
            int n = w * 32 + ct * 16 + m;
            float bv = b2[n];
            #pragma unroll
            for (int i = 0; i < 4; ++i) {
                float v = ssp(acc[ct][i] + bv);
                float u = __shfl_xor(v, 1, 64);
                if (!(lane & 1))
                    sm[S_TS + (q * 4 + i) * LSTRIDE + (n >> 1)] = pack2(v, u);
            }
        }
    }
    __syncthreads();
    stage_cp(sm, w3p, 2048, tid);
    __syncthreads();
    {   // h += Ts @ W3 + b3 ; As <- h_new
        f32x4 acc[2] = {{0,0,0,0},{0,0,0,0}};
        run_gemm<2>(sm, S_TS, lane, w * 32, acc);
        #pragma unroll
        for (int ct = 0; ct < 2; ++ct) {
            int n = w * 32 + ct * 16 + m;
            float bv = b3[n];
            #pragma unroll
            for (int i = 0; i < 4; ++i) {
                int r = rowbase + q * 4 + i;
                float hv = h[r * 128 + n] + acc[ct][i] + bv;
                h[r * 128 + n] = hv;
                float u = __shfl_xor(hv, 1, 64);
                if (!(lane & 1))
                    sm[S_AS + (q * 4 + i) * LSTRIDE + (n >> 1)] = pack2(hv, u);
            }
        }
    }
    __syncthreads();
    if (!LAST) {
        stage_cp(sm, w1np, 2048, tid);
        __syncthreads();
        f32x4 acc[2] = {{0,0,0,0},{0,0,0,0}};
        run_gemm<2>(sm, S_AS, lane, w * 32, acc);
        #pragma unroll
        for (int ct = 0; ct < 2; ++ct) {
            int n = w * 32 + ct * 16 + m;
            #pragma unroll
            for (int i = 0; i < 4; ++i) {
                float v = acc[ct][i];
                float u = __shfl_xor(v, 1, 64);
                if (!(lane & 1))
                    xout[(rowbase + q * 4 + i) * 64 + (n >> 1)] = pack2(v, u);
            }
        }
    } else {
        stage_cp(sm, w1np, 1024, tid);   // ow1^T (64 rows)
        __syncthreads();
        f32x4 acc[1] = {{0,0,0,0}};
        run_gemm<1>(sm, S_AS, lane, w * 16, acc);
        int n = w * 16 + m;
        float b1v = ob1[n], w2v = ow2[n];
        float part = 0.f;
        #pragma unroll
        for (int i = 0; i < 4; ++i) part += ssp(acc[0][i] + b1v) * w2v;
        #pragma unroll
        for (int mm = 1; mm < 64; mm <<= 1) part += __shfl_xor(part, mm, 64);
        float* fs = (float*)&sm[S_TS];
        if (lane == 0) fs[w] = part;
        __syncthreads();
        if (tid == 0) {
            float bsum = fs[0] + fs[1] + fs[2] + fs[3] + 16.0f * ob2[0];
            atomicAdd(&e_graph[bid >> 4], bsum);
        }
    }
}

// ---------------------------------------------------------------------------
__global__ void k_fin(const float* __restrict__ e_graph, const float* __restrict__ gbias,
                      float* __restrict__ out) {
    int tid = threadIdx.x;
    if (tid < NB) {
        float sb = 0.f;
        for (int j = 0; j < NB; ++j) sb += gbias[j];
        out[tid] = 32.0f * e_graph[tid] + sb;
    }
}

// ---------------------------------------------------------------------------
extern "C" void kernel_launch(void* const* d_in, const int* in_sizes, int n_in,
                              void* d_out, int out_size, void* d_ws, size_t ws_size,
                              hipStream_t stream) {
    SArgs a;
    a.pos  = (const float*)d_in[0];
    a.z    = (const int*)d_in[1];
    a.ei   = (const int*)d_in[3];
    a.dom  = (const int*)d_in[4];
    a.emb  = (const float*)d_in[5];
    a.mw1  = (const float*)d_in[6];
    a.mb1  = (const float*)d_in[7];
    a.mw2  = (const float*)d_in[8];
    a.mb2  = (const float*)d_in[9];
    a.cf1  = (const float*)d_in[10];
    a.cf2w = (const float*)d_in[11];
    const float* cf2b = (const float*)d_in[12];
    a.intw = (const float*)d_in[13];
    const float* intb = (const float*)d_in[14];
    a.ow1  = (const float*)d_in[15];
    const float* ob1  = (const float*)d_in[16];
    const float* ow2  = (const float*)d_in[17];
    const float* ob2  = (const float*)d_in[18];
    a.dome = (const float*)d_in[19];
    a.fw1  = (const float*)d_in[20];
    a.fb1  = (const float*)d_in[21];
    a.fw2  = (const float*)d_in[22];
    a.fb2  = (const float*)d_in[23];
    a.bw   = (const float*)d_in[26];
    a.bb   = (const float*)d_in[27];

    char* ws = (char*)d_ws;
    a.epack   = (uint2*)(ws + 0);               // 2 MB
    a.tab     = (uint*)(ws + 2*MB);             // 3 MB
    a.h       = (float*)(ws + 5*MB);            // 4 MB
    a.xA      = (uint*)(ws + 9*MB);             // 2 MB
    uint* xB  = (uint*)(ws + 11*MB);            // 2 MB
    a.e_graph = (float*)(ws + 13*MB);
    a.gbias   = (float*)(ws + 13*MB + 512);
    a.wpack   = (uint*)(ws + 13*MB + 4096);     // 606 KB
    a.out = (float*)d_out;
    a.out_size = out_size;

    k_setup<<<512, 256, 0, stream>>>(a);

    const uint* xr = a.xA;
    uint* xw = xB;
    for (int l = 0; l < NLAYER; ++l) {
        const uint* w2p  = a.wpack + (6 + l) * 8192;
        const uint* w3p  = a.wpack + (12 + l) * 8192;
        if (l < NLAYER - 1) {
            k_layer<false><<<512, 256, 0, stream>>>(
                a.h, xr, xw, a.tab + l*GTAB*64, a.epack, w2p, w3p,
                a.wpack + (l + 1) * 8192, cf2b + l*128, intb + l*128,
                ob1, ow2, ob2, a.e_graph);
        } else {
            k_layer<true><<<512, 256, 0, stream>>>(
                a.h, xr, xw, a.tab + l*GTAB*64, a.epack, w2p, w3p,
                a.wpack + OW1P_OFF, cf2b + l*128, intb + l*128,
                ob1, ow2, ob2, a.e_graph);
        }
        const uint* tmp = xr; xr = xw; xw = (uint*)tmp;
    }

    k_fin<<<1, 64, 0, stream>>>(a.e_graph, a.gbias, (float*)d_out);
}